// Round 3
// baseline (202.636 us; speedup 1.0000x reference)
//
#include <hip/hip_runtime.h>

// ClusterAggregator: B=8, N=32768, D=128, C=64, H=64
// out[b,c,:] = sum_{n: ca[b,n]==c} w_n * f[b,n,:], w = segment softmax of
// imp = sigmoid(relu(f@W1+b1)@W2+b2). Softmax shift-invariance: fixed shift 1
// (imp in (0,1)) -> e = exp(imp-1), exact after normalization.
// Matmul on bf16 MFMA 16x16x32. Flush via ws partials + reduce kernel
// (NO global atomics -- 4.2M fp32 atomics were the round-2 bottleneck:
// WRITE_SIZE 16.5MB == atomic count x 4B, memory-side RMW serialization).

#define B_ 8
#define N_ 32768
#define D_ 128
#define C_ 64
#define H_ 64

#define NTHREADS 256
#define NWAVES 4
#define ROWS_PER_BLOCK 512
#define NBLOCKS ((B_ * N_) / ROWS_PER_BLOCK)   // 512
#define SLICES (NBLOCKS / B_)                  // 64 blocks per batch
#define TILES 8            // 8 tiles * 16 rows = 128 rows per wave
#define FTS 136            // ushort stride of staged row (128 + 8 pad)

typedef float f32x4 __attribute__((ext_vector_type(4)));
typedef short s16x8 __attribute__((ext_vector_type(8)));

__device__ __forceinline__ short bf16rne(float x) {
    unsigned u = __float_as_uint(x);
    u = (u + 0x7FFFu + ((u >> 16) & 1u)) >> 16;
    return (short)u;
}
__device__ __forceinline__ float bf16tof(unsigned short s) {
    return __uint_as_float(((unsigned)s) << 16);
}

template <bool USE_WS>
__global__ __launch_bounds__(NTHREADS, 2)
void ca_fused_kernel(const float* __restrict__ features,
                     const int* __restrict__ ca,
                     const float* __restrict__ W1,
                     const float* __restrict__ b1,
                     const float* __restrict__ W2,
                     const float* __restrict__ b2,
                     float* __restrict__ out_sums,   // atomic path: [B*C*D]
                     float* __restrict__ denoms,     // atomic path: [B*C]
                     float* __restrict__ pout,       // ws path: [NBLOCKS][C*D]
                     float* __restrict__ pden)       // ws path: [NBLOCKS][C]
{
    __shared__ float bins[C_ * D_];                      // 32 KB
    __shared__ float dbins[C_];
    __shared__ unsigned short ftile[NWAVES][16 * FTS];   // 17 KB (bf16 rows)

    const int tid  = threadIdx.x;
    const int lane = tid & 63;
    const int wave = tid >> 6;
    const int m    = lane & 15;   // A-row / B-col index within fragment
    const int kb   = lane >> 4;   // k-group

    const int b = blockIdx.x / SLICES;

    for (int i = tid; i < C_ * D_; i += NTHREADS) bins[i] = 0.f;
    if (tid < C_) dbins[tid] = 0.f;

    // B fragments (persistent): bfr[ks][nt][j] = bf16(W1[ks*32+kb*8+j][nt*16+m])
    s16x8 bfr[4][4];
#pragma unroll
    for (int ks = 0; ks < 4; ++ks)
#pragma unroll
        for (int nt = 0; nt < 4; ++nt)
#pragma unroll
            for (int j = 0; j < 8; ++j)
                bfr[ks][nt][j] = bf16rne(W1[(ks * 32 + kb * 8 + j) * H_ + nt * 16 + m]);

    float b1v[4], w2v[4];
#pragma unroll
    for (int nt = 0; nt < 4; ++nt) {
        b1v[nt] = b1[nt * 16 + m];
        w2v[nt] = W2[nt * 16 + m];
    }
    const float b2v = b2[0];

    __syncthreads();

    unsigned short* ftw = &ftile[wave][0];
    const int row_block0 = blockIdx.x * ROWS_PER_BLOCK;

    for (int t = 0; t < TILES; ++t) {
        const int row0 = row_block0 + wave * (16 * TILES) + t * 16;
        const long long grow = row0 + m;
        const float4* fp = (const float4*)features + grow * 32;

        // cluster ids for the 16 rows (lane r < 16 holds row r's id)
        int cv = 0;
        if (lane < 16) cv = ca[row0 + lane];

        // ---- load 16x128 tile, convert to bf16 A-frags, stage bf16 to LDS
        s16x8 af[4];
#pragma unroll
        for (int ks = 0; ks < 4; ++ks) {
            const float4 fa = fp[ks * 8 + kb * 2];
            const float4 fb = fp[ks * 8 + kb * 2 + 1];
            s16x8 a;
            a[0] = bf16rne(fa.x); a[1] = bf16rne(fa.y);
            a[2] = bf16rne(fa.z); a[3] = bf16rne(fa.w);
            a[4] = bf16rne(fb.x); a[5] = bf16rne(fb.y);
            a[6] = bf16rne(fb.z); a[7] = bf16rne(fb.w);
            af[ks] = a;
            *reinterpret_cast<s16x8*>(&ftw[m * FTS + ks * 32 + kb * 8]) = a;
        }

        // ---- MFMA: h[16 rows][64] = f @ W1
        f32x4 acc[4];
#pragma unroll
        for (int nt = 0; nt < 4; ++nt) acc[nt] = (f32x4){0.f, 0.f, 0.f, 0.f};
#pragma unroll
        for (int ks = 0; ks < 4; ++ks)
#pragma unroll
            for (int nt = 0; nt < 4; ++nt)
                acc[nt] = __builtin_amdgcn_mfma_f32_16x16x32_bf16(
                    af[ks], bfr[ks][nt], acc[nt], 0, 0, 0);

        // ---- epilogue: relu, @W2, sigmoid, e = exp(imp-1)
        // acc[nt][r] = h[row=(lane>>4)*4+r][hcol=nt*16+(lane&15)]
        float p[4];
#pragma unroll
        for (int r = 0; r < 4; ++r) {
            float s = 0.f;
#pragma unroll
            for (int nt = 0; nt < 4; ++nt)
                s = fmaf(fmaxf(acc[nt][r] + b1v[nt], 0.f), w2v[nt], s);
#pragma unroll
            for (int off = 1; off < 16; off <<= 1)
                s += __shfl_xor(s, off, 64);
            const float pre = s + b2v;
            const float imp = 1.f / (1.f + __expf(-pre));
            p[r] = __expf(imp - 1.f);
        }
        // lane provides e for row 4*(lane>>4)+(lane&3); fetch e for row m
        const int q = lane & 3;
        const float prov = (q == 0) ? p[0] : (q == 1) ? p[1] : (q == 2) ? p[2] : p[3];
        const int srcl = ((m >> 2) << 4) | (m & 3);
        const float eL = __shfl(prov, srcl, 64);   // e for row (lane&15)
        if (lane < 16) atomicAdd(&dbins[cv], eL);

        // (compiler inserts the lgkmcnt waits for ftw write->read; no asm
        //  clobber so loads for tile t+1 can pipeline above this loop)

        // ---- aggregate: one row per instruction, d = lane (conflict-free)
#pragma unroll
        for (int r = 0; r < 16; ++r) {
            const float e = __shfl(eL, r, 64);   // const lane -> v_readlane
            const int   c = __shfl(cv, r, 64);
            const float v0 = bf16tof(ftw[r * FTS + lane]);
            const float v1 = bf16tof(ftw[r * FTS + 64 + lane]);
            atomicAdd(&bins[c * D_ + lane],      e * v0);
            atomicAdd(&bins[c * D_ + 64 + lane], e * v1);
        }
    }

    __syncthreads();
    if (USE_WS) {
        // plain streaming stores of the block's partial (no atomics)
        float* po = pout + (size_t)blockIdx.x * (C_ * D_);
        for (int i = tid; i < C_ * D_; i += NTHREADS) po[i] = bins[i];
        if (tid < C_) pden[blockIdx.x * C_ + tid] = dbins[tid];
    } else {
        for (int i = tid; i < C_ * D_; i += NTHREADS)
            atomicAdd(&out_sums[b * (C_ * D_) + i], bins[i]);
        if (tid < C_) atomicAdd(&denoms[b * C_ + tid], dbins[tid]);
    }
}

// Reduce SLICES partials per (b,c), divide by reduced denom, write out.
__global__ __launch_bounds__(D_)
void ca_reduce_kernel(const float* __restrict__ pout,
                      const float* __restrict__ pden,
                      float* __restrict__ out)
{
    const int bc = blockIdx.x;           // 0 .. B_*C_-1
    const int b  = bc >> 6;
    const int c  = bc & (C_ - 1);
    const int d  = threadIdx.x;

    float s = 0.f;
#pragma unroll 4
    for (int sl = 0; sl < SLICES; ++sl)
        s += pout[((size_t)(b * SLICES + sl)) * (C_ * D_) + c * D_ + d];

    float dn = 0.f;   // uniform across threads -> scalar loads
#pragma unroll 4
    for (int sl = 0; sl < SLICES; ++sl)
        dn += pden[(b * SLICES + sl) * C_ + c];

    out[(size_t)bc * D_ + d] = (dn > 0.f) ? (s / dn) : 0.f;
}

__global__ void ca_zero_kernel(float* __restrict__ out_sums,
                               float* __restrict__ denoms)
{
    const int i = blockIdx.x * blockDim.x + threadIdx.x;
    if (i < B_ * C_ * D_) out_sums[i] = 0.f;
    if (i < B_ * C_)      denoms[i] = 0.f;
}

__global__ void ca_finalize_kernel(float* __restrict__ out_sums,
                                   const float* __restrict__ denoms)
{
    const int i = blockIdx.x * blockDim.x + threadIdx.x;
    if (i >= B_ * C_ * D_) return;
    const int bc = i >> 7;
    const float den = denoms[bc];
    const float v = out_sums[i];
    out_sums[i] = (den > 0.f) ? (v / den) : 0.f;
}

extern "C" void kernel_launch(void* const* d_in, const int* in_sizes, int n_in,
                              void* d_out, int out_size, void* d_ws, size_t ws_size,
                              hipStream_t stream) {
    const float* features = (const float*)d_in[0];
    const int*   ca       = (const int*)  d_in[1];
    const float* W1       = (const float*)d_in[2];
    const float* b1       = (const float*)d_in[3];
    const float* W2       = (const float*)d_in[4];
    const float* b2       = (const float*)d_in[5];

    float* out = (float*)d_out;   // [B*C*D]

    const size_t pout_elems = (size_t)NBLOCKS * C_ * D_;   // 4,194,304
    const size_t pden_elems = (size_t)NBLOCKS * C_;        // 32,768
    const size_t need = (pout_elems + pden_elems) * sizeof(float);  // ~16.9 MB

    if (ws_size >= need) {
        float* pout = (float*)d_ws;
        float* pden = pout + pout_elems;
        ca_fused_kernel<true><<<NBLOCKS, NTHREADS, 0, stream>>>(
            features, ca, W1, b1, W2, b2, nullptr, nullptr, pout, pden);
        ca_reduce_kernel<<<B_ * C_, D_, 0, stream>>>(pout, pden, out);
    } else {
        // fallback: global-atomic flush (correct, slower)
        float* denoms = (float*)d_ws;   // [B*C]
        ca_zero_kernel<<<(B_ * C_ * D_ + 255) / 256, 256, 0, stream>>>(out, denoms);
        ca_fused_kernel<false><<<NBLOCKS, NTHREADS, 0, stream>>>(
            features, ca, W1, b1, W2, b2, out, denoms, nullptr, nullptr);
        ca_finalize_kernel<<<(B_ * C_ * D_ + 255) / 256, 256, 0, stream>>>(out, denoms);
    }
}

// Round 6
// 169.178 us; speedup vs baseline: 1.1978x; 1.1978x over previous
//
#include <hip/hip_runtime.h>
#include <hip/hip_bf16.h>

// ClusterAggregator: B=8, N=32768, D=128, C=64, H=64
// out[b,c,:] = sum_{n: ca[b,n]==c} w_n * f[b,n,:], w = segment softmax of
// imp = sigmoid(relu(f@W1+b1)@W2+b2). Softmax shift-invariance: fixed shift 1
// (imp in (0,1)) -> e = exp(imp-1), exact after normalization.
//
// R6: MFMA one-hot aggregation (S[c,d] += sum_r (e_r*onehot[c,r]) * f[r,d],
// accumulated in registers, ZERO per-row LDS atomics) with the B-operand
// obtained from an LDS tile staged ALREADY-TRANSPOSED: ft[d][r], stride 40
// ushorts. Write: 32 scalar ds_write_b16 per half-tile (plain, pipelined).
// Read: one aligned ds_read_b128 per B-frag (standard semantics).
// ds_read_b64_tr_b16 is gone -- R4/R5 failed on its unverifiable addressing.

#define B_ 8
#define N_ 32768
#define D_ 128
#define C_ 64
#define H_ 64

#define NTHREADS 256
#define NWAVES 4
#define ROWS_PER_BLOCK 512
#define NBLOCKS ((B_ * N_) / ROWS_PER_BLOCK)   // 512
#define SLICES (NBLOCKS / B_)                  // 64 blocks per batch
#define RST 40   // ushort stride of ft rows: 80B (16B-aligned, 2-way read banks)

typedef float f32x4 __attribute__((ext_vector_type(4)));
typedef short s16x8 __attribute__((ext_vector_type(8)));

__device__ __forceinline__ short bf16rne(float x) {
    unsigned u = __float_as_uint(x);
    u = (u + 0x7FFFu + ((u >> 16) & 1u)) >> 16;
    return (short)u;
}

__device__ __forceinline__ s16x8 pk8(float4 a, float4 b) {
    union { s16x8 v; __hip_bfloat162 h[4]; } u;
    u.h[0] = __float22bfloat162_rn(make_float2(a.x, a.y));
    u.h[1] = __float22bfloat162_rn(make_float2(a.z, a.w));
    u.h[2] = __float22bfloat162_rn(make_float2(b.x, b.y));
    u.h[3] = __float22bfloat162_rn(make_float2(b.z, b.w));
    return u.v;
}

template <bool USE_WS>
__global__ __launch_bounds__(NTHREADS, 2)
void ca_fused_kernel(const float* __restrict__ features,
                     const int* __restrict__ ca,
                     const float* __restrict__ b1,
                     const float* __restrict__ W2,
                     const float* __restrict__ b2,
                     const unsigned short* __restrict__ w1t,  // bf16 W1^T [64][128]
                     float* __restrict__ out_sums,   // atomic path: [B*C*D]
                     float* __restrict__ denoms,     // atomic path: [B*C]
                     float* __restrict__ pout,       // ws path: [NBLOCKS][C*D]
                     float* __restrict__ pden)       // ws path: [NBLOCKS][C]
{
    // ft (wave-private transposed stage, main loop) unioned with bins (reduce)
    __shared__ __align__(16) unsigned short gst[NWAVES][128 * RST];  // 40 KB
    __shared__ __align__(16) unsigned long long ce[NWAVES][32];      // (c,e)/row
    __shared__ float dbins[C_];

    const int tid  = threadIdx.x;
    const int lane = tid & 63;
    const int wave = tid >> 6;
    const int m    = lane & 15;
    const int kb   = lane >> 4;
    const int bidx = blockIdx.x;
    const int b    = bidx / SLICES;

    float b1v[4], w2v[4];
#pragma unroll
    for (int nt = 0; nt < 4; ++nt) {
        b1v[nt] = b1[nt * 16 + m];
        w2v[nt] = W2[nt * 16 + m];
    }
    const float b2v = b2[0];

    // aggregation accumulators: S[chunk(c/16)][nt(d/16)] fragments + den
    f32x4 accS[4][8];
    f32x4 accD[4];
#pragma unroll
    for (int c4 = 0; c4 < 4; ++c4) {
        accD[c4] = (f32x4){0.f, 0.f, 0.f, 0.f};
#pragma unroll
        for (int nt = 0; nt < 8; ++nt) accS[c4][nt] = (f32x4){0.f, 0.f, 0.f, 0.f};
    }

    // ones-column B fragment for denominator MFMA: B[k][n] = (n==0)
    s16x8 bones;
    {
        const short o = (m == 0) ? (short)0x3F80 : (short)0;
#pragma unroll
        for (int j = 0; j < 8; ++j) bones[j] = o;
    }

    unsigned short* ftw = &gst[wave][0];
    unsigned long long* cew = &ce[wave][0];

    const int rbase = bidx * ROWS_PER_BLOCK + wave * 128;

    for (int g = 0; g < 4; ++g) {
#pragma unroll
        for (int half = 0; half < 2; ++half) {
            const int row0 = rbase + g * 32 + half * 16;
            const float4* fp = (const float4*)features + (long long)(row0 + m) * 32;
            int cv = 0;
            if (lane < 16) cv = ca[row0 + lane];

            // load 16x128 fp32 rows (lane m owns row half*16+m) -> bf16 frags
            s16x8 af[4];
#pragma unroll
            for (int ks = 0; ks < 4; ++ks) {
                const float4 fa = fp[ks * 8 + kb * 2];
                const float4 fb = fp[ks * 8 + kb * 2 + 1];
                af[ks] = pk8(fa, fb);
            }

            // stage TRANSPOSED: ft[d][r] = f[r][d]; d = ks*32+kb*8+j, r = half*16+m
            const int r = half * 16 + m;
#pragma unroll
            for (int ks = 0; ks < 4; ++ks)
#pragma unroll
                for (int j = 0; j < 8; ++j)
                    ftw[(ks * 32 + kb * 8 + j) * RST + r] = (unsigned short)af[ks][j];

            // h = f @ W1 (B-frags streamed from L2-hot bf16 W1^T)
            f32x4 hacc[4];
#pragma unroll
            for (int nt = 0; nt < 4; ++nt) hacc[nt] = (f32x4){0.f, 0.f, 0.f, 0.f};
#pragma unroll
            for (int ks = 0; ks < 4; ++ks) {
#pragma unroll
                for (int nt = 0; nt < 4; ++nt) {
                    const s16x8 w = *(const s16x8*)(w1t + (nt * 16 + m) * 128 +
                                                    ks * 32 + kb * 8);
                    hacc[nt] = __builtin_amdgcn_mfma_f32_16x16x32_bf16(
                        af[ks], w, hacc[nt], 0, 0, 0);
                }
            }

            // epilogue: relu, @W2, sigmoid, e = exp(imp-1)
            // hacc[nt][rr] = h[row=kb*4+rr][hcol=nt*16+m]
            float p[4];
#pragma unroll
            for (int rr = 0; rr < 4; ++rr) {
                float s = 0.f;
#pragma unroll
                for (int nt = 0; nt < 4; ++nt)
                    s = fmaf(fmaxf(hacc[nt][rr] + b1v[nt], 0.f), w2v[nt], s);
#pragma unroll
                for (int off = 1; off < 16; off <<= 1)
                    s += __shfl_xor(s, off, 64);
                const float pre = s + b2v;
                const float imp = 1.f / (1.f + __expf(-pre));
                p[rr] = __expf(imp - 1.f);
            }
            // lane provides e for row 4*kb+(lane&3); fetch e for row m
            const int q = lane & 3;
            const float prov = (q == 0) ? p[0] : (q == 1) ? p[1] : (q == 2) ? p[2] : p[3];
            const int srcl = ((m >> 2) << 4) | (m & 3);
            const float eL = __shfl(prov, srcl, 64);   // e for row (lane&15)
            if (lane < 16)
                cew[half * 16 + lane] =
                    ((unsigned long long)__float_as_uint(eL) << 32) | (unsigned)cv;
        }

        // ---- 32-row group aggregation: S += (e*onehot) @ f  (all-MFMA) ----
        // (c,e) for rows kb*8 .. kb*8+7 (this lane's k-slots)
        const ulonglong2* cp = (const ulonglong2*)&ce[wave][kb * 8];
        const ulonglong2 q0 = cp[0], q1 = cp[1], q2 = cp[2], q3 = cp[3];
        int cc[8]; short eb[8];
        cc[0] = (int)(unsigned)q0.x; eb[0] = bf16rne(__uint_as_float((unsigned)(q0.x >> 32)));
        cc[1] = (int)(unsigned)q0.y; eb[1] = bf16rne(__uint_as_float((unsigned)(q0.y >> 32)));
        cc[2] = (int)(unsigned)q1.x; eb[2] = bf16rne(__uint_as_float((unsigned)(q1.x >> 32)));
        cc[3] = (int)(unsigned)q1.y; eb[3] = bf16rne(__uint_as_float((unsigned)(q1.y >> 32)));
        cc[4] = (int)(unsigned)q2.x; eb[4] = bf16rne(__uint_as_float((unsigned)(q2.x >> 32)));
        cc[5] = (int)(unsigned)q2.y; eb[5] = bf16rne(__uint_as_float((unsigned)(q2.y >> 32)));
        cc[6] = (int)(unsigned)q3.x; eb[6] = bf16rne(__uint_as_float((unsigned)(q3.x >> 32)));
        cc[7] = (int)(unsigned)q3.y; eb[7] = bf16rne(__uint_as_float((unsigned)(q3.y >> 32)));

        // A-frags: afr[chunk][j] = (c_{kb*8+j} == chunk*16+m) ? bf16(e) : 0
        s16x8 afr[4];
#pragma unroll
        for (int c4 = 0; c4 < 4; ++c4)
#pragma unroll
            for (int j = 0; j < 8; ++j)
                afr[c4][j] = (cc[j] == c4 * 16 + m) ? eb[j] : (short)0;

        // B-frags: bf[j] = f[kb*8+j][nt*16+m] = ft[nt*16+m][kb*8+j]
        // one aligned ds_read_b128 per nt (8 ushorts, j-contiguous)
#pragma unroll
        for (int nt = 0; nt < 8; ++nt) {
            const s16x8 bfv = *(const s16x8*)&ftw[(nt * 16 + m) * RST + kb * 8];
            accS[0][nt] = __builtin_amdgcn_mfma_f32_16x16x32_bf16(afr[0], bfv, accS[0][nt], 0, 0, 0);
            accS[1][nt] = __builtin_amdgcn_mfma_f32_16x16x32_bf16(afr[1], bfv, accS[1][nt], 0, 0, 0);
            accS[2][nt] = __builtin_amdgcn_mfma_f32_16x16x32_bf16(afr[2], bfv, accS[2][nt], 0, 0, 0);
            accS[3][nt] = __builtin_amdgcn_mfma_f32_16x16x32_bf16(afr[3], bfv, accS[3][nt], 0, 0, 0);
        }
#pragma unroll
        for (int c4 = 0; c4 < 4; ++c4)
            accD[c4] = __builtin_amdgcn_mfma_f32_16x16x32_bf16(afr[c4], bones, accD[c4], 0, 0, 0);
    }

    // ---- cross-wave reduce in LDS (reuse ft space as fp32 bins), flush ----
    __syncthreads();
    float* bins = (float*)&gst[0][0];   // 8192 floats = 32 KB (fits in 40 KB)
    for (int i = tid; i < C_ * D_; i += NTHREADS) bins[i] = 0.f;
    if (tid < C_) dbins[tid] = 0.f;
    __syncthreads();
#pragma unroll
    for (int c4 = 0; c4 < 4; ++c4)
#pragma unroll
        for (int nt = 0; nt < 8; ++nt)
#pragma unroll
            for (int qq = 0; qq < 4; ++qq)
                atomicAdd(&bins[(c4 * 16 + kb * 4 + qq) * D_ + nt * 16 + m],
                          accS[c4][nt][qq]);
    if (m == 0) {
#pragma unroll
        for (int c4 = 0; c4 < 4; ++c4)
#pragma unroll
            for (int qq = 0; qq < 4; ++qq)
                atomicAdd(&dbins[c4 * 16 + kb * 4 + qq], accD[c4][qq]);
    }
    __syncthreads();

    if (USE_WS) {
        float* po = pout + (size_t)bidx * (C_ * D_);
        for (int i = tid; i < C_ * D_; i += NTHREADS) po[i] = bins[i];
        if (tid < C_) pden[bidx * C_ + tid] = dbins[tid];
    } else {
        for (int i = tid; i < C_ * D_; i += NTHREADS)
            atomicAdd(&out_sums[b * (C_ * D_) + i], bins[i]);
        if (tid < C_) atomicAdd(&denoms[b * C_ + tid], dbins[tid]);
    }
}

// bf16 W1^T prep: w1t[h*128+k] = bf16(W1[k*64+h])
__global__ void ca_w1t_prep(const float* __restrict__ W1,
                            unsigned short* __restrict__ w1t)
{
    const int i = blockIdx.x * blockDim.x + threadIdx.x;
    if (i < H_ * D_) {
        const int h = i >> 7, k = i & 127;
        w1t[i] = (unsigned short)bf16rne(W1[k * H_ + h]);
    }
}

// Reduce SLICES partials per (b,c), divide by reduced denom, write out.
__global__ __launch_bounds__(D_)
void ca_reduce_kernel(const float* __restrict__ pout,
                      const float* __restrict__ pden,
                      float* __restrict__ out)
{
    const int bc = blockIdx.x;           // 0 .. B_*C_-1
    const int b  = bc >> 6;
    const int c  = bc & (C_ - 1);
    const int d  = threadIdx.x;

    float s = 0.f;
#pragma unroll 4
    for (int sl = 0; sl < SLICES; ++sl)
        s += pout[((size_t)(b * SLICES + sl)) * (C_ * D_) + c * D_ + d];

    float dn = 0.f;   // uniform across threads -> scalar loads
#pragma unroll 4
    for (int sl = 0; sl < SLICES; ++sl)
        dn += pden[(b * SLICES + sl) * C_ + c];

    out[(size_t)bc * D_ + d] = (dn > 0.f) ? (s / dn) : 0.f;
}

__global__ void ca_zero_kernel(float* __restrict__ out_sums,
                               float* __restrict__ denoms)
{
    const int i = blockIdx.x * blockDim.x + threadIdx.x;
    if (i < B_ * C_ * D_) out_sums[i] = 0.f;
    if (i < B_ * C_)      denoms[i] = 0.f;
}

__global__ void ca_finalize_kernel(float* __restrict__ out_sums,
                                   const float* __restrict__ denoms)
{
    const int i = blockIdx.x * blockDim.x + threadIdx.x;
    if (i >= B_ * C_ * D_) return;
    const int bc = i >> 7;
    const float den = denoms[bc];
    const float v = out_sums[i];
    out_sums[i] = (den > 0.f) ? (v / den) : 0.f;
}

extern "C" void kernel_launch(void* const* d_in, const int* in_sizes, int n_in,
                              void* d_out, int out_size, void* d_ws, size_t ws_size,
                              hipStream_t stream) {
    const float* features = (const float*)d_in[0];
    const int*   ca       = (const int*)  d_in[1];
    const float* W1       = (const float*)d_in[2];
    const float* b1       = (const float*)d_in[3];
    const float* W2       = (const float*)d_in[4];
    const float* b2       = (const float*)d_in[5];

    float* out = (float*)d_out;   // [B*C*D]

    // ws layout: [w1t 16KB][pden 128KB][pout 16MB]
    unsigned short* w1t = (unsigned short*)d_ws;
    float* pden = (float*)((char*)d_ws + 16384);
    float* pout = (float*)((char*)d_ws + 16384 + 131072);
    const size_t need_full = 16384 + 131072 + (size_t)NBLOCKS * C_ * D_ * 4;

    ca_w1t_prep<<<(H_ * D_ + 255) / 256, 256, 0, stream>>>(W1, w1t);

    if (ws_size >= need_full) {
        ca_fused_kernel<true><<<NBLOCKS, NTHREADS, 0, stream>>>(
            features, ca, b1, W2, b2, w1t, nullptr, nullptr, pout, pden);
        ca_reduce_kernel<<<B_ * C_, D_, 0, stream>>>(pout, pden, out);
    } else {
        // fallback: global-atomic flush (needs only w1t + pden prefix)
        ca_zero_kernel<<<(B_ * C_ * D_ + 255) / 256, 256, 0, stream>>>(out, pden);
        ca_fused_kernel<false><<<NBLOCKS, NTHREADS, 0, stream>>>(
            features, ca, b1, W2, b2, w1t, out, pden, nullptr, nullptr);
        ca_finalize_kernel<<<(B_ * C_ * D_ + 255) / 256, 256, 0, stream>>>(out, pden);
    }
}

// Round 7
// 69.064 us; speedup vs baseline: 2.9340x; 2.4496x over previous
//
#include <hip/hip_runtime.h>
#include <hip/hip_bf16.h>

// ClusterAggregator: B=8, N=32768, D=128, C=64, H=64
// out[b,c,:] = sum_{n: ca[b,n]==c} w_n * f[b,n,:], w = segment softmax of
// imp = sigmoid(relu(f@W1+b1)@W2+b2). Softmax shift-invariance: fixed shift 1.
//
// R7: Little's-law fix. R1/R2/R6 all ~200us with every pipe <6% busy ->
// latency-bound, ~0.2KB/wave in flight. Now: async global_load_lds staging
// (dbuf, counted vmcnt(2), XOR-pre-swizzled source), 16 waves/CU, and the
// HW-validated one-hot MFMA aggregation with accumulators SPLIT across 8
// waves (one (c-chunk,d-half) each: accS=16 VGPRs, no spill).

#define B_ 8
#define N_ 32768
#define D_ 128
#define C_ 64
#define H_ 64

#define NTHREADS 512
#define NWAVES 8
#define ROWS_PER_BLOCK 512
#define NBLOCKS ((B_ * N_) / ROWS_PER_BLOCK)   // 512
#define SLICES (NBLOCKS / B_)                  // 64
#define NSTEPS 16                              // 32 rows per step
#define RST 40    // ft ushort stride (80 B: 16B-aligned rows)
#define W1S 136   // w1l ushort stride

typedef float f32x4 __attribute__((ext_vector_type(4)));
typedef short s16x8 __attribute__((ext_vector_type(8)));

__device__ __forceinline__ short bf16rne(float x) {
    unsigned u = __float_as_uint(x);
    u = (u + 0x7FFFu + ((u >> 16) & 1u)) >> 16;
    return (short)u;
}

__device__ __forceinline__ s16x8 pk8(float4 a, float4 b) {
    union { s16x8 v; __hip_bfloat162 h[4]; } u;
    u.h[0] = __float22bfloat162_rn(make_float2(a.x, a.y));
    u.h[1] = __float22bfloat162_rn(make_float2(a.z, a.w));
    u.h[2] = __float22bfloat162_rn(make_float2(b.x, b.y));
    u.h[3] = __float22bfloat162_rn(make_float2(b.z, b.w));
    return u.v;
}

__device__ __forceinline__ void gload16(const void* g, void* l) {
    __builtin_amdgcn_global_load_lds(
        (const __attribute__((address_space(1))) unsigned int*)g,
        (__attribute__((address_space(3))) unsigned int*)l, 16, 0, 0);
}

template <bool USE_WS>
__global__ __launch_bounds__(NTHREADS, 4)   // 4 waves/EU = 16 waves/CU
void ca_fused_kernel(const float* __restrict__ features,
                     const int* __restrict__ ca,
                     const float* __restrict__ b1,
                     const float* __restrict__ W2,
                     const float* __restrict__ b2,
                     const unsigned short* __restrict__ w1t,  // bf16 W1^T [64][128]
                     float* __restrict__ out_sums,   // atomic path: [B*C*D]
                     float* __restrict__ denoms,     // atomic path: [B*C]
                     float* __restrict__ pout,       // ws path: [NBLOCKS][C*D]
                     float* __restrict__ pden)       // ws path: [NBLOCKS][C]
{
    __shared__ __align__(16) unsigned char stageb[2][16384];   // 32 KB fp32 dbuf
    __shared__ __align__(16) unsigned short ft[D_ * RST];      // 10 KB bf16 f^T
    __shared__ __align__(16) unsigned short w1l[H_ * W1S];     // 17 KB bf16 W1^T
    __shared__ __align__(16) unsigned long long ce[32];        // (c,e) per row

    const int tid  = threadIdx.x;
    const int lane = tid & 63;
    const int wave = tid >> 6;
    const int m    = lane & 15;
    const int kb   = lane >> 4;
    const int bidx = blockIdx.x;
    const int b    = bidx / SLICES;
    const int row_blk0 = bidx * ROWS_PER_BLOCK;

    // W1^T into LDS (padded stride; reads are b128 per frag)
    for (int i = tid; i < H_ * D_; i += NTHREADS) {
        const int h = i >> 7, k = i & 127;
        w1l[h * W1S + k] = w1t[i];
    }

    float b1v[4], w2v[4];
#pragma unroll
    for (int nt = 0; nt < 4; ++nt) {
        b1v[nt] = b1[nt * 16 + m];
        w2v[nt] = W2[nt * 16 + m];
    }
    const float b2v = b2[0];

    const int CH = wave >> 1;   // this wave's cluster chunk (16 clusters)
    const int dh = wave & 1;    // this wave's d-half (64 dims)

    f32x4 accS[4];
    f32x4 accD = (f32x4){0.f, 0.f, 0.f, 0.f};
#pragma unroll
    for (int nt = 0; nt < 4; ++nt) accS[nt] = (f32x4){0.f, 0.f, 0.f, 0.f};

    // ones-column B fragment for denominator MFMA: B[k][n] = (n==0)
    s16x8 bones;
    {
        const short o = (m == 0) ? (short)0x3F80 : (short)0;
#pragma unroll
        for (int j = 0; j < 8; ++j) bones[j] = o;
    }

    // async stage of tile t (32 rows, 16 KB) into stageb[buf]; XOR-pre-swizzled
    // source so reads at [r*512 + (col ^ ((r&7)<<4))] return f[r][col] (rule 21).
    auto stage_issue = [&](int t, int buf) {
#pragma unroll
        for (int i = 0; i < 2; ++i) {
            const int chunk = wave * 2 + i;                 // 0..15, wave-uniform
            const int r   = chunk * 2 + (lane >> 5);        // 0..31
            const int col = (lane & 31) * 16;
            const long long src =
                (long long)(row_blk0 + t * 32 + r) * 512 + (col ^ ((r & 7) << 4));
            gload16((const char*)features + src, &stageb[buf][chunk * 1024]);
        }
    };

    stage_issue(0, 0);

    for (int s = 0; s < NSTEPS; ++s) {
        const int tn = (s + 1 < NSTEPS) ? s + 1 : NSTEPS - 1;   // dummy re-stage ok
        stage_issue(tn, (s + 1) & 1);
        asm volatile("s_waitcnt vmcnt(2)" ::: "memory");  // my step-s loads landed
        __syncthreads();  // all waves' loads landed; prev phase-B done -> ft free

        // ---- phase A: 2 owner waves compute e for the 32 rows ----
        const int ow0 = (2 * s) & 7;
        if (wave == ow0 || wave == ow0 + 1) {
            const int owx  = wave - ow0;          // 0 or 1
            const int rloc = owx * 16 + m;        // row within tile
            const unsigned char* sb = stageb[s & 1];
            const int swz = (rloc & 7) << 4;

            s16x8 af[4];
#pragma unroll
            for (int ks = 0; ks < 4; ++ks) {
                const int oa = ks * 128 + kb * 32;
                const float4 fa = *(const float4*)(sb + rloc * 512 + (oa ^ swz));
                const float4 fb = *(const float4*)(sb + rloc * 512 + ((oa + 16) ^ swz));
                af[ks] = pk8(fa, fb);
#pragma unroll
                for (int j = 0; j < 8; ++j)   // bf16 f^T for aggregation B-frags
                    ft[(ks * 32 + kb * 8 + j) * RST + rloc] = (unsigned short)af[ks][j];
            }

            // h = f @ W1
            f32x4 hacc[4];
#pragma unroll
            for (int nt = 0; nt < 4; ++nt) hacc[nt] = (f32x4){0.f, 0.f, 0.f, 0.f};
#pragma unroll
            for (int ks = 0; ks < 4; ++ks)
#pragma unroll
                for (int nt = 0; nt < 4; ++nt) {
                    const s16x8 w = *(const s16x8*)&w1l[(nt * 16 + m) * W1S +
                                                        ks * 32 + kb * 8];
                    hacc[nt] = __builtin_amdgcn_mfma_f32_16x16x32_bf16(
                        af[ks], w, hacc[nt], 0, 0, 0);
                }

            // epilogue: relu, @W2, sigmoid, e = exp(imp-1)  (R6-validated)
            float p[4];
#pragma unroll
            for (int rr = 0; rr < 4; ++rr) {
                float sv = 0.f;
#pragma unroll
                for (int nt = 0; nt < 4; ++nt)
                    sv = fmaf(fmaxf(hacc[nt][rr] + b1v[nt], 0.f), w2v[nt], sv);
#pragma unroll
                for (int off = 1; off < 16; off <<= 1)
                    sv += __shfl_xor(sv, off, 64);
                const float pre = sv + b2v;
                const float imp = 1.f / (1.f + __expf(-pre));
                p[rr] = __expf(imp - 1.f);
            }
            const int q = lane & 3;
            const float prov = (q == 0) ? p[0] : (q == 1) ? p[1] : (q == 2) ? p[2] : p[3];
            const int srcl = ((m >> 2) << 4) | (m & 3);
            const float eL = __shfl(prov, srcl, 64);   // e for row (lane&15)
            int cv = 0;
            if (lane < 16) cv = ca[row_blk0 + s * 32 + owx * 16 + lane];
            if (lane < 16)
                ce[owx * 16 + lane] =
                    ((unsigned long long)__float_as_uint(eL) << 32) | (unsigned)cv;
        }
        __syncthreads();

        // ---- phase B: all 8 waves aggregate their (CH, dh) slice ----
        const ulonglong2* cp = (const ulonglong2*)&ce[kb * 8];
        const ulonglong2 q0 = cp[0], q1 = cp[1], q2 = cp[2], q3 = cp[3];
        int cc[8]; short eb[8];
        cc[0] = (int)(unsigned)q0.x; eb[0] = bf16rne(__uint_as_float((unsigned)(q0.x >> 32)));
        cc[1] = (int)(unsigned)q0.y; eb[1] = bf16rne(__uint_as_float((unsigned)(q0.y >> 32)));
        cc[2] = (int)(unsigned)q1.x; eb[2] = bf16rne(__uint_as_float((unsigned)(q1.x >> 32)));
        cc[3] = (int)(unsigned)q1.y; eb[3] = bf16rne(__uint_as_float((unsigned)(q1.y >> 32)));
        cc[4] = (int)(unsigned)q2.x; eb[4] = bf16rne(__uint_as_float((unsigned)(q2.x >> 32)));
        cc[5] = (int)(unsigned)q2.y; eb[5] = bf16rne(__uint_as_float((unsigned)(q2.y >> 32)));
        cc[6] = (int)(unsigned)q3.x; eb[6] = bf16rne(__uint_as_float((unsigned)(q3.x >> 32)));
        cc[7] = (int)(unsigned)q3.y; eb[7] = bf16rne(__uint_as_float((unsigned)(q3.y >> 32)));

        s16x8 afr;
#pragma unroll
        for (int j = 0; j < 8; ++j)
            afr[j] = (cc[j] == CH * 16 + m) ? eb[j] : (short)0;

#pragma unroll
        for (int nt = 0; nt < 4; ++nt) {
            const int d0 = (dh * 4 + nt) * 16 + m;
            const s16x8 bfv = *(const s16x8*)&ft[d0 * RST + kb * 8];
            accS[nt] = __builtin_amdgcn_mfma_f32_16x16x32_bf16(afr, bfv, accS[nt], 0, 0, 0);
        }
        if (dh == 0)
            accD = __builtin_amdgcn_mfma_f32_16x16x32_bf16(afr, bones, accD, 0, 0, 0);
        __syncthreads();   // ft/ce reusable next step
    }

    // ---- flush: each wave's slice is disjoint -> plain stores (ws path) ----
#pragma unroll
    for (int nt = 0; nt < 4; ++nt)
#pragma unroll
        for (int qq = 0; qq < 4; ++qq) {
            const int idx = (CH * 16 + kb * 4 + qq) * D_ + (dh * 4 + nt) * 16 + m;
            if (USE_WS) pout[(size_t)bidx * (C_ * D_) + idx] = accS[nt][qq];
            else atomicAdd(&out_sums[b * (C_ * D_) + idx], accS[nt][qq]);
        }
    if (dh == 0 && m == 0) {
#pragma unroll
        for (int qq = 0; qq < 4; ++qq) {
            const int c = CH * 16 + kb * 4 + qq;
            if (USE_WS) pden[bidx * C_ + c] = accD[qq];
            else atomicAdd(&denoms[b * C_ + c], accD[qq]);
        }
    }
}

// bf16 W1^T prep: w1t[h*128+k] = bf16(W1[k*64+h])
__global__ void ca_w1t_prep(const float* __restrict__ W1,
                            unsigned short* __restrict__ w1t)
{
    const int i = blockIdx.x * blockDim.x + threadIdx.x;
    if (i < H_ * D_) {
        const int h = i >> 7, k = i & 127;
        w1t[i] = (unsigned short)bf16rne(W1[k * H_ + h]);
    }
}

// Reduce SLICES partials per (b,c), divide by reduced denom, write out.
__global__ __launch_bounds__(D_)
void ca_reduce_kernel(const float* __restrict__ pout,
                      const float* __restrict__ pden,
                      float* __restrict__ out)
{
    const int bc = blockIdx.x;           // 0 .. B_*C_-1
    const int b  = bc >> 6;
    const int c  = bc & (C_ - 1);
    const int d  = threadIdx.x;

    float s = 0.f;
#pragma unroll 4
    for (int sl = 0; sl < SLICES; ++sl)
        s += pout[((size_t)(b * SLICES + sl)) * (C_ * D_) + c * D_ + d];

    float dn = 0.f;   // uniform across threads -> scalar loads
#pragma unroll 4
    for (int sl = 0; sl < SLICES; ++sl)
        dn += pden[(b * SLICES + sl) * C_ + c];

    out[(size_t)bc * D_ + d] = (dn > 0.f) ? (s / dn) : 0.f;
}

__global__ void ca_zero_kernel(float* __restrict__ out_sums,
                               float* __restrict__ denoms)
{
    const int i = blockIdx.x * blockDim.x + threadIdx.x;
    if (i < B_ * C_ * D_) out_sums[i] = 0.f;
    if (i < B_ * C_)      denoms[i] = 0.f;
}

__global__ void ca_finalize_kernel(float* __restrict__ out_sums,
                                   const float* __restrict__ denoms)
{
    const int i = blockIdx.x * blockDim.x + threadIdx.x;
    if (i >= B_ * C_ * D_) return;
    const int bc = i >> 7;
    const float den = denoms[bc];
    const float v = out_sums[i];
    out_sums[i] = (den > 0.f) ? (v / den) : 0.f;
}

extern "C" void kernel_launch(void* const* d_in, const int* in_sizes, int n_in,
                              void* d_out, int out_size, void* d_ws, size_t ws_size,
                              hipStream_t stream) {
    const float* features = (const float*)d_in[0];
    const int*   ca       = (const int*)  d_in[1];
    const float* W1       = (const float*)d_in[2];
    const float* b1       = (const float*)d_in[3];
    const float* W2       = (const float*)d_in[4];
    const float* b2       = (const float*)d_in[5];

    float* out = (float*)d_out;   // [B*C*D]

    // ws layout: [w1t 16KB][pden 128KB][pout 16MB]
    unsigned short* w1t = (unsigned short*)d_ws;
    float* pden = (float*)((char*)d_ws + 16384);
    float* pout = (float*)((char*)d_ws + 16384 + 131072);
    const size_t need_full = 16384 + 131072 + (size_t)NBLOCKS * C_ * D_ * 4;

    ca_w1t_prep<<<(H_ * D_ + 255) / 256, 256, 0, stream>>>(W1, w1t);

    if (ws_size >= need_full) {
        ca_fused_kernel<true><<<NBLOCKS, NTHREADS, 0, stream>>>(
            features, ca, b1, W2, b2, w1t, nullptr, nullptr, pout, pden);
        ca_reduce_kernel<<<B_ * C_, D_, 0, stream>>>(pout, pden, out);
    } else {
        // fallback: global-atomic flush (needs only w1t + pden prefix)
        ca_zero_kernel<<<(B_ * C_ * D_ + 255) / 256, 256, 0, stream>>>(out, pden);
        ca_fused_kernel<false><<<NBLOCKS, NTHREADS, 0, stream>>>(
            features, ca, b1, W2, b2, w1t, out, pden, nullptr, nullptr);
        ca_finalize_kernel<<<(B_ * C_ * D_ + 255) / 256, 256, 0, stream>>>(out, pden);
    }
}

// Round 8
// 62.603 us; speedup vs baseline: 3.2368x; 1.1032x over previous
//
#include <hip/hip_runtime.h>
#include <hip/hip_bf16.h>

// ClusterAggregator: B=8, N=32768, D=128, C=64, H=64
// out[b,c,:] = sum_{n: ca[b,n]==c} w_n * f[b,n,:], w = segment softmax of
// imp = sigmoid(relu(f@W1+b1)@W2+b2). Softmax shift-invariance: fixed shift 1.
//
// R8: all-waves super-steps. R7 fixed latency (169->~50us fused) but ran
// phase A on only 2/8 waves per step. Now: 128-row super-steps, EVERY wave
// does phase A on its own 16 rows (register-prefetched one super-step ahead,
// ~8KB/wave in flight), then all waves phase-B their (c-chunk, d-half) slice
// over 4 k-groups. 2 barriers per super-step. LDS 53KB -> 2 blocks/CU.

#define B_ 8
#define N_ 32768
#define D_ 128
#define C_ 64
#define H_ 64

#define NTHREADS 512
#define NWAVES 8
#define ROWS_PER_BLOCK 512
#define NBLOCKS ((B_ * N_) / ROWS_PER_BLOCK)   // 512
#define SLICES (NBLOCKS / B_)                  // 64
#define NSS 4                                  // super-steps of 128 rows
#define RST 136   // ft ushort stride (272 B; b128-aligned)
#define W1S 136   // w1l ushort stride

typedef float f32x4 __attribute__((ext_vector_type(4)));
typedef short s16x8 __attribute__((ext_vector_type(8)));

__device__ __forceinline__ short bf16rne(float x) {
    unsigned u = __float_as_uint(x);
    u = (u + 0x7FFFu + ((u >> 16) & 1u)) >> 16;
    return (short)u;
}

__device__ __forceinline__ s16x8 pk8(float4 a, float4 b) {
    union { s16x8 v; __hip_bfloat162 h[4]; } u;
    u.h[0] = __float22bfloat162_rn(make_float2(a.x, a.y));
    u.h[1] = __float22bfloat162_rn(make_float2(a.z, a.w));
    u.h[2] = __float22bfloat162_rn(make_float2(b.x, b.y));
    u.h[3] = __float22bfloat162_rn(make_float2(b.z, b.w));
    return u.v;
}

template <bool USE_WS>
__global__ __launch_bounds__(NTHREADS, 4)   // 4 waves/EU -> 16 waves/CU
void ca_fused_kernel(const float* __restrict__ features,
                     const int* __restrict__ ca,
                     const float* __restrict__ b1,
                     const float* __restrict__ W2,
                     const float* __restrict__ b2,
                     const unsigned short* __restrict__ w1t,  // bf16 W1^T [64][128]
                     float* __restrict__ out_sums,   // atomic path: [B*C*D]
                     float* __restrict__ denoms,     // atomic path: [B*C]
                     float* __restrict__ pout,       // ws path: [NBLOCKS][C*D]
                     float* __restrict__ pden)       // ws path: [NBLOCKS][C]
{
    __shared__ __align__(16) unsigned short ft[D_ * RST];   // 34.8 KB bf16 f^T
    __shared__ __align__(16) unsigned short w1l[H_ * W1S];  // 17.4 KB bf16 W1^T
    __shared__ __align__(16) unsigned long long ce[128];    // (c,e) per row

    const int tid  = threadIdx.x;
    const int lane = tid & 63;
    const int wave = tid >> 6;
    const int m    = lane & 15;
    const int kb   = lane >> 4;
    const int bidx = blockIdx.x;
    const int b    = bidx / SLICES;
    const int row_blk0 = bidx * ROWS_PER_BLOCK;

    // W1^T into LDS (padded stride; phase-A reads are one b128 per frag)
    for (int i = tid; i < H_ * D_; i += NTHREADS) {
        const int h = i >> 7, k = i & 127;
        w1l[h * W1S + k] = w1t[i];
    }

    float b1v[4], w2v[4];
#pragma unroll
    for (int nt = 0; nt < 4; ++nt) {
        b1v[nt] = b1[nt * 16 + m];
        w2v[nt] = W2[nt * 16 + m];
    }
    const float b2v = b2[0];

    const int CH = wave >> 1;   // this wave's cluster chunk (16 clusters)
    const int dh = wave & 1;    // this wave's d-half (64 dims)

    f32x4 accS[4];
    f32x4 accD = (f32x4){0.f, 0.f, 0.f, 0.f};
#pragma unroll
    for (int nt = 0; nt < 4; ++nt) accS[nt] = (f32x4){0.f, 0.f, 0.f, 0.f};

    // ones-column B fragment for denominator MFMA: B[k][n] = (n==0)
    s16x8 bones;
    {
        const short o = (m == 0) ? (short)0x3F80 : (short)0;
#pragma unroll
        for (int j = 0; j < 8; ++j) bones[j] = o;
    }

    // ---- register prefetch for super-step 0: lane owns row wave*16+m ----
    // pf[2ks],pf[2ks+1] = f[row][ks*32+kb*8 .. +7]  (8 x dwordx4 in flight)
    const float* fbase = features + (long long)(row_blk0 + wave * 16 + m) * D_;
    float4 pf[8];
#pragma unroll
    for (int ks = 0; ks < 4; ++ks) {
        pf[2 * ks]     = *(const float4*)(fbase + ks * 32 + kb * 8);
        pf[2 * ks + 1] = *(const float4*)(fbase + ks * 32 + kb * 8 + 4);
    }
    int cv = 0;
    if (lane < 16) cv = ca[row_blk0 + wave * 16 + lane];

    __syncthreads();   // w1l ready

#pragma unroll
    for (int ss = 0; ss < NSS; ++ss) {
        // consume prefetch -> bf16 A-frags
        s16x8 af[4];
#pragma unroll
        for (int ks = 0; ks < 4; ++ks) af[ks] = pk8(pf[2 * ks], pf[2 * ks + 1]);
        const int cvc = cv;

        // issue prefetch for next super-step (stays in flight through A+B)
        if (ss + 1 < NSS) {
            const float* fn = fbase + (ss + 1) * 128 * D_;
#pragma unroll
            for (int ks = 0; ks < 4; ++ks) {
                pf[2 * ks]     = *(const float4*)(fn + ks * 32 + kb * 8);
                pf[2 * ks + 1] = *(const float4*)(fn + ks * 32 + kb * 8 + 4);
            }
            if (lane < 16) cv = ca[row_blk0 + (ss + 1) * 128 + wave * 16 + lane];
        }

        // ---- phase A: stage ft (transposed bf16) + h-matmul + epilogue ----
        const int r = wave * 16 + m;   // global row within 128-row super-tile
#pragma unroll
        for (int ks = 0; ks < 4; ++ks)
#pragma unroll
            for (int j = 0; j < 8; ++j)
                ft[(ks * 32 + kb * 8 + j) * RST + r] = (unsigned short)af[ks][j];

        f32x4 hacc[4];
#pragma unroll
        for (int nt = 0; nt < 4; ++nt) hacc[nt] = (f32x4){0.f, 0.f, 0.f, 0.f};
#pragma unroll
        for (int ks = 0; ks < 4; ++ks)
#pragma unroll
            for (int nt = 0; nt < 4; ++nt) {
                const s16x8 w = *(const s16x8*)&w1l[(nt * 16 + m) * W1S +
                                                    ks * 32 + kb * 8];
                hacc[nt] = __builtin_amdgcn_mfma_f32_16x16x32_bf16(
                    af[ks], w, hacc[nt], 0, 0, 0);
            }

        // relu, @W2, sigmoid, e = exp(imp-1)   (HW-validated R6/R7 path)
        float p[4];
#pragma unroll
        for (int rr = 0; rr < 4; ++rr) {
            float sv = 0.f;
#pragma unroll
            for (int nt = 0; nt < 4; ++nt)
                sv = fmaf(fmaxf(hacc[nt][rr] + b1v[nt], 0.f), w2v[nt], sv);
#pragma unroll
            for (int off = 1; off < 16; off <<= 1)
                sv += __shfl_xor(sv, off, 64);
            const float pre = sv + b2v;
            const float imp = 1.f / (1.f + __expf(-pre));
            p[rr] = __expf(imp - 1.f);
        }
        const int q = lane & 3;
        const float prov = (q == 0) ? p[0] : (q == 1) ? p[1] : (q == 2) ? p[2] : p[3];
        const int srcl = ((m >> 2) << 4) | (m & 3);
        const float eL = __shfl(prov, srcl, 64);   // e for local row (lane&15)
        if (lane < 16)
            ce[wave * 16 + lane] =
                ((unsigned long long)__float_as_uint(eL) << 32) | (unsigned)cvc;

        __syncthreads();   // ft + ce complete for all 128 rows

        // ---- phase B: every wave aggregates its (CH, dh) slice, 4 k-groups --
#pragma unroll
        for (int kg = 0; kg < 4; ++kg) {
            const ulonglong2* cp = (const ulonglong2*)&ce[kg * 32 + kb * 8];
            const ulonglong2 q0 = cp[0], q1 = cp[1], q2 = cp[2], q3 = cp[3];
            int cc[8]; short eb[8];
            cc[0] = (int)(unsigned)q0.x; eb[0] = bf16rne(__uint_as_float((unsigned)(q0.x >> 32)));
            cc[1] = (int)(unsigned)q0.y; eb[1] = bf16rne(__uint_as_float((unsigned)(q0.y >> 32)));
            cc[2] = (int)(unsigned)q1.x; eb[2] = bf16rne(__uint_as_float((unsigned)(q1.x >> 32)));
            cc[3] = (int)(unsigned)q1.y; eb[3] = bf16rne(__uint_as_float((unsigned)(q1.y >> 32)));
            cc[4] = (int)(unsigned)q2.x; eb[4] = bf16rne(__uint_as_float((unsigned)(q2.x >> 32)));
            cc[5] = (int)(unsigned)q2.y; eb[5] = bf16rne(__uint_as_float((unsigned)(q2.y >> 32)));
            cc[6] = (int)(unsigned)q3.x; eb[6] = bf16rne(__uint_as_float((unsigned)(q3.x >> 32)));
            cc[7] = (int)(unsigned)q3.y; eb[7] = bf16rne(__uint_as_float((unsigned)(q3.y >> 32)));

            s16x8 afr;
#pragma unroll
            for (int j = 0; j < 8; ++j)
                afr[j] = (cc[j] == CH * 16 + m) ? eb[j] : (short)0;

#pragma unroll
            for (int nt = 0; nt < 4; ++nt) {
                const int d0 = (dh * 4 + nt) * 16 + m;
                const s16x8 bfv = *(const s16x8*)&ft[d0 * RST + kg * 32 + kb * 8];
                accS[nt] = __builtin_amdgcn_mfma_f32_16x16x32_bf16(
                    afr, bfv, accS[nt], 0, 0, 0);
            }
            if (dh == 0)
                accD = __builtin_amdgcn_mfma_f32_16x16x32_bf16(afr, bones, accD, 0, 0, 0);
        }
        __syncthreads();   // ft/ce reusable next super-step
    }

    // ---- flush: per-wave slices disjoint -> plain stores (ws path) ----
#pragma unroll
    for (int nt = 0; nt < 4; ++nt)
#pragma unroll
        for (int qq = 0; qq < 4; ++qq) {
            const int idx = (CH * 16 + kb * 4 + qq) * D_ + (dh * 4 + nt) * 16 + m;
            if (USE_WS) pout[(size_t)bidx * (C_ * D_) + idx] = accS[nt][qq];
            else atomicAdd(&out_sums[b * (C_ * D_) + idx], accS[nt][qq]);
        }
    if (dh == 0 && m == 0) {
#pragma unroll
        for (int qq = 0; qq < 4; ++qq) {
            const int c = CH * 16 + kb * 4 + qq;
            if (USE_WS) pden[bidx * C_ + c] = accD[qq];
            else atomicAdd(&denoms[b * C_ + c], accD[qq]);
        }
    }
}

// bf16 W1^T prep: w1t[h*128+k] = bf16(W1[k*64+h])
__global__ void ca_w1t_prep(const float* __restrict__ W1,
                            unsigned short* __restrict__ w1t)
{
    const int i = blockIdx.x * blockDim.x + threadIdx.x;
    if (i < H_ * D_) {
        const int h = i >> 7, k = i & 127;
        w1t[i] = (unsigned short)bf16rne(W1[k * H_ + h]);
    }
}

// Reduce SLICES partials per (b,c), divide by reduced denom, write out.
__global__ __launch_bounds__(D_)
void ca_reduce_kernel(const float* __restrict__ pout,
                      const float* __restrict__ pden,
                      float* __restrict__ out)
{
    const int bc = blockIdx.x;           // 0 .. B_*C_-1
    const int b  = bc >> 6;
    const int c  = bc & (C_ - 1);
    const int d  = threadIdx.x;

    float s = 0.f;
#pragma unroll 4
    for (int sl = 0; sl < SLICES; ++sl)
        s += pout[((size_t)(b * SLICES + sl)) * (C_ * D_) + c * D_ + d];

    float dn = 0.f;   // uniform across threads -> scalar loads
#pragma unroll 4
    for (int sl = 0; sl < SLICES; ++sl)
        dn += pden[(b * SLICES + sl) * C_ + c];

    out[(size_t)bc * D_ + d] = (dn > 0.f) ? (s / dn) : 0.f;
}

__global__ void ca_zero_kernel(float* __restrict__ out_sums,
                               float* __restrict__ denoms)
{
    const int i = blockIdx.x * blockDim.x + threadIdx.x;
    if (i < B_ * C_ * D_) out_sums[i] = 0.f;
    if (i < B_ * C_)      denoms[i] = 0.f;
}

__global__ void ca_finalize_kernel(float* __restrict__ out_sums,
                                   const float* __restrict__ denoms)
{
    const int i = blockIdx.x * blockDim.x + threadIdx.x;
    if (i >= B_ * C_ * D_) return;
    const int bc = i >> 7;
    const float den = denoms[bc];
    const float v = out_sums[i];
    out_sums[i] = (den > 0.f) ? (v / den) : 0.f;
}

extern "C" void kernel_launch(void* const* d_in, const int* in_sizes, int n_in,
                              void* d_out, int out_size, void* d_ws, size_t ws_size,
                              hipStream_t stream) {
    const float* features = (const float*)d_in[0];
    const int*   ca       = (const int*)  d_in[1];
    const float* W1       = (const float*)d_in[2];
    const float* b1       = (const float*)d_in[3];
    const float* W2       = (const float*)d_in[4];
    const float* b2       = (const float*)d_in[5];

    float* out = (float*)d_out;   // [B*C*D]

    // ws layout: [w1t 16KB][pden 128KB][pout 16MB]
    unsigned short* w1t = (unsigned short*)d_ws;
    float* pden = (float*)((char*)d_ws + 16384);
    float* pout = (float*)((char*)d_ws + 16384 + 131072);
    const size_t need_full = 16384 + 131072 + (size_t)NBLOCKS * C_ * D_ * 4;

    ca_w1t_prep<<<(H_ * D_ + 255) / 256, 256, 0, stream>>>(W1, w1t);

    if (ws_size >= need_full) {
        ca_fused_kernel<true><<<NBLOCKS, NTHREADS, 0, stream>>>(
            features, ca, b1, W2, b2, w1t, nullptr, nullptr, pout, pden);
        ca_reduce_kernel<<<B_ * C_, D_, 0, stream>>>(pout, pden, out);
    } else {
        // fallback: global-atomic flush (needs only w1t + pden prefix)
        ca_zero_kernel<<<(B_ * C_ * D_ + 255) / 256, 256, 0, stream>>>(out, pden);
        ca_fused_kernel<false><<<NBLOCKS, NTHREADS, 0, stream>>>(
            features, ca, b1, W2, b2, w1t, out, pden, nullptr, nullptr);
        ca_finalize_kernel<<<(B_ * C_ * D_ + 255) / 256, 256, 0, stream>>>(out, pden);
    }
}

// Round 9
// 51.210 us; speedup vs baseline: 3.9569x; 1.2225x over previous
//
#include <hip/hip_runtime.h>
#include <hip/hip_bf16.h>

// ClusterAggregator: B=8, N=32768, D=128, C=64, H=64
// out[b,c,:] = sum_{n: ca[b,n]==c} w_n * f[b,n,:], w = segment softmax of
// imp = sigmoid(relu(f@W1+b1)@W2+b2). Softmax shift-invariance: fixed shift 1.
//
// R9: overhead round. Fused core identical to R8 (all-waves 128-row
// super-steps, register prefetch 1 step ahead, one-hot MFMA aggregation,
// per-wave disjoint accumulator slices). Changes:
//  - W1 bf16-transpose folded into the fused kernel (prep kernel removed)
//  - reduce kernel: 512 threads/block, 16 slices/thread + LDS combine,
//    denominator via one wave-reduce (was 64 serial scalar loads)

#define B_ 8
#define N_ 32768
#define D_ 128
#define C_ 64
#define H_ 64

#define NTHREADS 512
#define NWAVES 8
#define ROWS_PER_BLOCK 512
#define NBLOCKS ((B_ * N_) / ROWS_PER_BLOCK)   // 512
#define SLICES (NBLOCKS / B_)                  // 64
#define NSS 4                                  // super-steps of 128 rows
#define RST 136   // ft ushort stride (272 B; b128-aligned)
#define W1S 136   // w1l ushort stride

typedef float f32x4 __attribute__((ext_vector_type(4)));
typedef short s16x8 __attribute__((ext_vector_type(8)));

__device__ __forceinline__ short bf16rne(float x) {
    unsigned u = __float_as_uint(x);
    u = (u + 0x7FFFu + ((u >> 16) & 1u)) >> 16;
    return (short)u;
}

__device__ __forceinline__ s16x8 pk8(float4 a, float4 b) {
    union { s16x8 v; __hip_bfloat162 h[4]; } u;
    u.h[0] = __float22bfloat162_rn(make_float2(a.x, a.y));
    u.h[1] = __float22bfloat162_rn(make_float2(a.z, a.w));
    u.h[2] = __float22bfloat162_rn(make_float2(b.x, b.y));
    u.h[3] = __float22bfloat162_rn(make_float2(b.z, b.w));
    return u.v;
}

template <bool USE_WS>
__global__ __launch_bounds__(NTHREADS, 4)   // 4 waves/EU -> 16 waves/CU
void ca_fused_kernel(const float* __restrict__ features,
                     const int* __restrict__ ca,
                     const float* __restrict__ b1,
                     const float* __restrict__ W2,
                     const float* __restrict__ b2,
                     const float* __restrict__ W1,   // fp32 [128][64]
                     float* __restrict__ out_sums,   // atomic path: [B*C*D]
                     float* __restrict__ denoms,     // atomic path: [B*C]
                     float* __restrict__ pout,       // ws path: [NBLOCKS][C*D]
                     float* __restrict__ pden)       // ws path: [NBLOCKS][C]
{
    __shared__ __align__(16) unsigned short ft[D_ * RST];   // 34.8 KB bf16 f^T
    __shared__ __align__(16) unsigned short w1l[H_ * W1S];  // 17.4 KB bf16 W1^T
    __shared__ __align__(16) unsigned long long ce[128];    // (c,e) per row

    const int tid  = threadIdx.x;
    const int lane = tid & 63;
    const int wave = tid >> 6;
    const int m    = lane & 15;
    const int kb   = lane >> 4;
    const int bidx = blockIdx.x;
    const int b    = bidx / SLICES;
    const int row_blk0 = bidx * ROWS_PER_BLOCK;

    // W1 (fp32, coalesced) -> bf16 W1^T in LDS: w1l[h][k] = bf16(W1[k][h])
    for (int i = tid; i < H_ * D_; i += NTHREADS) {
        const int k = i >> 6, h = i & 63;
        w1l[h * W1S + k] = (unsigned short)bf16rne(W1[i]);
    }

    float b1v[4], w2v[4];
#pragma unroll
    for (int nt = 0; nt < 4; ++nt) {
        b1v[nt] = b1[nt * 16 + m];
        w2v[nt] = W2[nt * 16 + m];
    }
    const float b2v = b2[0];

    const int CH = wave >> 1;   // this wave's cluster chunk (16 clusters)
    const int dh = wave & 1;    // this wave's d-half (64 dims)

    f32x4 accS[4];
    f32x4 accD = (f32x4){0.f, 0.f, 0.f, 0.f};
#pragma unroll
    for (int nt = 0; nt < 4; ++nt) accS[nt] = (f32x4){0.f, 0.f, 0.f, 0.f};

    // ones-column B fragment for denominator MFMA: B[k][n] = (n==0)
    s16x8 bones;
    {
        const short o = (m == 0) ? (short)0x3F80 : (short)0;
#pragma unroll
        for (int j = 0; j < 8; ++j) bones[j] = o;
    }

    // ---- register prefetch for super-step 0: lane owns row wave*16+m ----
    const float* fbase = features + (long long)(row_blk0 + wave * 16 + m) * D_;
    float4 pf[8];
#pragma unroll
    for (int ks = 0; ks < 4; ++ks) {
        pf[2 * ks]     = *(const float4*)(fbase + ks * 32 + kb * 8);
        pf[2 * ks + 1] = *(const float4*)(fbase + ks * 32 + kb * 8 + 4);
    }
    int cv = 0;
    if (lane < 16) cv = ca[row_blk0 + wave * 16 + lane];

    __syncthreads();   // w1l ready

#pragma unroll
    for (int ss = 0; ss < NSS; ++ss) {
        // consume prefetch -> bf16 A-frags
        s16x8 af[4];
#pragma unroll
        for (int ks = 0; ks < 4; ++ks) af[ks] = pk8(pf[2 * ks], pf[2 * ks + 1]);
        const int cvc = cv;

        // issue prefetch for next super-step (stays in flight through A+B)
        if (ss + 1 < NSS) {
            const float* fn = fbase + (ss + 1) * 128 * D_;
#pragma unroll
            for (int ks = 0; ks < 4; ++ks) {
                pf[2 * ks]     = *(const float4*)(fn + ks * 32 + kb * 8);
                pf[2 * ks + 1] = *(const float4*)(fn + ks * 32 + kb * 8 + 4);
            }
            if (lane < 16) cv = ca[row_blk0 + (ss + 1) * 128 + wave * 16 + lane];
        }

        // ---- phase A: stage ft (transposed bf16) + h-matmul + epilogue ----
        const int r = wave * 16 + m;   // row within 128-row super-tile
#pragma unroll
        for (int ks = 0; ks < 4; ++ks)
#pragma unroll
            for (int j = 0; j < 8; ++j)
                ft[(ks * 32 + kb * 8 + j) * RST + r] = (unsigned short)af[ks][j];

        f32x4 hacc[4];
#pragma unroll
        for (int nt = 0; nt < 4; ++nt) hacc[nt] = (f32x4){0.f, 0.f, 0.f, 0.f};
#pragma unroll
        for (int ks = 0; ks < 4; ++ks)
#pragma unroll
            for (int nt = 0; nt < 4; ++nt) {
                const s16x8 w = *(const s16x8*)&w1l[(nt * 16 + m) * W1S +
                                                    ks * 32 + kb * 8];
                hacc[nt] = __builtin_amdgcn_mfma_f32_16x16x32_bf16(
                    af[ks], w, hacc[nt], 0, 0, 0);
            }

        // relu, @W2, sigmoid, e = exp(imp-1)   (HW-validated path)
        float p[4];
#pragma unroll
        for (int rr = 0; rr < 4; ++rr) {
            float sv = 0.f;
#pragma unroll
            for (int nt = 0; nt < 4; ++nt)
                sv = fmaf(fmaxf(hacc[nt][rr] + b1v[nt], 0.f), w2v[nt], sv);
#pragma unroll
            for (int off = 1; off < 16; off <<= 1)
                sv += __shfl_xor(sv, off, 64);
            const float pre = sv + b2v;
            const float imp = 1.f / (1.f + __expf(-pre));
            p[rr] = __expf(imp - 1.f);
        }
        const int q = lane & 3;
        const float prov = (q == 0) ? p[0] : (q == 1) ? p[1] : (q == 2) ? p[2] : p[3];
        const int srcl = ((m >> 2) << 4) | (m & 3);
        const float eL = __shfl(prov, srcl, 64);   // e for local row (lane&15)
        if (lane < 16)
            ce[wave * 16 + lane] =
                ((unsigned long long)__float_as_uint(eL) << 32) | (unsigned)cvc;

        __syncthreads();   // ft + ce complete for all 128 rows

        // ---- phase B: every wave aggregates its (CH, dh) slice, 4 k-groups --
#pragma unroll
        for (int kg = 0; kg < 4; ++kg) {
            const ulonglong2* cp = (const ulonglong2*)&ce[kg * 32 + kb * 8];
            const ulonglong2 q0 = cp[0], q1 = cp[1], q2 = cp[2], q3 = cp[3];
            int cc[8]; short eb[8];
            cc[0] = (int)(unsigned)q0.x; eb[0] = bf16rne(__uint_as_float((unsigned)(q0.x >> 32)));
            cc[1] = (int)(unsigned)q0.y; eb[1] = bf16rne(__uint_as_float((unsigned)(q0.y >> 32)));
            cc[2] = (int)(unsigned)q1.x; eb[2] = bf16rne(__uint_as_float((unsigned)(q1.x >> 32)));
            cc[3] = (int)(unsigned)q1.y; eb[3] = bf16rne(__uint_as_float((unsigned)(q1.y >> 32)));
            cc[4] = (int)(unsigned)q2.x; eb[4] = bf16rne(__uint_as_float((unsigned)(q2.x >> 32)));
            cc[5] = (int)(unsigned)q2.y; eb[5] = bf16rne(__uint_as_float((unsigned)(q2.y >> 32)));
            cc[6] = (int)(unsigned)q3.x; eb[6] = bf16rne(__uint_as_float((unsigned)(q3.x >> 32)));
            cc[7] = (int)(unsigned)q3.y; eb[7] = bf16rne(__uint_as_float((unsigned)(q3.y >> 32)));

            s16x8 afr;
#pragma unroll
            for (int j = 0; j < 8; ++j)
                afr[j] = (cc[j] == CH * 16 + m) ? eb[j] : (short)0;

#pragma unroll
            for (int nt = 0; nt < 4; ++nt) {
                const int d0 = (dh * 4 + nt) * 16 + m;
                const s16x8 bfv = *(const s16x8*)&ft[d0 * RST + kg * 32 + kb * 8];
                accS[nt] = __builtin_amdgcn_mfma_f32_16x16x32_bf16(
                    afr, bfv, accS[nt], 0, 0, 0);
            }
            if (dh == 0)
                accD = __builtin_amdgcn_mfma_f32_16x16x32_bf16(afr, bones, accD, 0, 0, 0);
        }
        __syncthreads();   // ft/ce reusable next super-step
    }

    // ---- flush: per-wave slices disjoint -> plain stores (ws path) ----
#pragma unroll
    for (int nt = 0; nt < 4; ++nt)
#pragma unroll
        for (int qq = 0; qq < 4; ++qq) {
            const int idx = (CH * 16 + kb * 4 + qq) * D_ + (dh * 4 + nt) * 16 + m;
            if (USE_WS) pout[(size_t)bidx * (C_ * D_) + idx] = accS[nt][qq];
            else atomicAdd(&out_sums[b * (C_ * D_) + idx], accS[nt][qq]);
        }
    if (dh == 0 && m == 0) {
#pragma unroll
        for (int qq = 0; qq < 4; ++qq) {
            const int c = CH * 16 + kb * 4 + qq;
            if (USE_WS) pden[bidx * C_ + c] = accD[qq];
            else atomicAdd(&denoms[b * C_ + c], accD[qq]);
        }
    }
}

// Reduce SLICES partials per (b,c), divide by reduced denom, write out.
// 512 threads: thread t sums 16 slices of element d=t&127 (group sg=t>>7),
// LDS combine 4->1; denominator wave-reduced from 64 lanes.
__global__ __launch_bounds__(512)
void ca_reduce_kernel(const float* __restrict__ pout,
                      const float* __restrict__ pden,
                      float* __restrict__ out)
{
    __shared__ float red[512];
    __shared__ float dns;

    const int bc = blockIdx.x;           // 0 .. B_*C_-1
    const int b  = bc >> 6;
    const int c  = bc & (C_ - 1);
    const int t  = threadIdx.x;
    const int d  = t & 127;
    const int sg = t >> 7;               // 0..3

    const float* pb = pout + ((size_t)(b * SLICES + sg * 16)) * (C_ * D_)
                           + c * D_ + d;
    float s = 0.f;
#pragma unroll 4
    for (int i = 0; i < 16; ++i) s += pb[(size_t)i * (C_ * D_)];
    red[t] = s;

    float dnv = 0.f;
    if (t < SLICES) dnv = pden[(b * SLICES + t) * C_ + c];
    if (t < 64) {
#pragma unroll
        for (int off = 32; off > 0; off >>= 1) dnv += __shfl_xor(dnv, off, 64);
        if (t == 0) dns = dnv;
    }
    __syncthreads();

    if (t < 128) {
        const float tot = red[t] + red[t + 128] + red[t + 256] + red[t + 384];
        const float dn = dns;
        out[(size_t)bc * D_ + t] = (dn > 0.f) ? (tot / dn) : 0.f;
    }
}

__global__ void ca_zero_kernel(float* __restrict__ out_sums,
                               float* __restrict__ denoms)
{
    const int i = blockIdx.x * blockDim.x + threadIdx.x;
    if (i < B_ * C_ * D_) out_sums[i] = 0.f;
    if (i < B_ * C_)      denoms[i] = 0.f;
}

__global__ void ca_finalize_kernel(float* __restrict__ out_sums,
                                   const float* __restrict__ denoms)
{
    const int i = blockIdx.x * blockDim.x + threadIdx.x;
    if (i >= B_ * C_ * D_) return;
    const int bc = i >> 7;
    const float den = denoms[bc];
    const float v = out_sums[i];
    out_sums[i] = (den > 0.f) ? (v / den) : 0.f;
}

extern "C" void kernel_launch(void* const* d_in, const int* in_sizes, int n_in,
                              void* d_out, int out_size, void* d_ws, size_t ws_size,
                              hipStream_t stream) {
    const float* features = (const float*)d_in[0];
    const int*   ca       = (const int*)  d_in[1];
    const float* W1       = (const float*)d_in[2];
    const float* b1       = (const float*)d_in[3];
    const float* W2       = (const float*)d_in[4];
    const float* b2       = (const float*)d_in[5];

    float* out = (float*)d_out;   // [B*C*D]

    // ws layout: [pden 128KB][pout 16MB]
    float* pden = (float*)d_ws;
    float* pout = (float*)((char*)d_ws + 131072);
    const size_t need_full = 131072 + (size_t)NBLOCKS * C_ * D_ * 4;

    if (ws_size >= need_full) {
        ca_fused_kernel<true><<<NBLOCKS, NTHREADS, 0, stream>>>(
            features, ca, b1, W2, b2, W1, nullptr, nullptr, pout, pden);
        ca_reduce_kernel<<<B_ * C_, 512, 0, stream>>>(pout, pden, out);
    } else {
        // fallback: global-atomic flush (needs only pden prefix, 2 KB)
        ca_zero_kernel<<<(B_ * C_ * D_ + 255) / 256, 256, 0, stream>>>(out, pden);
        ca_fused_kernel<false><<<NBLOCKS, NTHREADS, 0, stream>>>(
            features, ca, b1, W2, b2, W1, out, pden, nullptr, nullptr);
        ca_finalize_kernel<<<(B_ * C_ * D_ + 255) / 256, 256, 0, stream>>>(out, pden);
    }
}